// Round 4
// baseline (583.755 us; speedup 1.0000x reference)
//
#include <hip/hip_runtime.h>
#include <hip/hip_bf16.h>

// N=1048576, D_IN=48, D_ATT=8
// Algebra: scores = Wq G Wk^T/sqrt(8), G = x^T x  [48x48]
//          v = x @ Wv^T  [N x 8]  (materialized bf16 in pass 1)
//          out = v @ W2, W2 = softmax(scores) Wo^T  [8x48]
// Pass 1 (k_gram_v): G via bf16 MFMA + fused v=x@Wv^T. 1024 blocks.
//   G partials -> 32 copies (atomics). Then last-block-closer (threadfence +
//   counter) sums copies + softmax epilogue -> Mt2. (k_combine folded in; one
//   fewer dispatch + no 1-block kernel bubble.)
// Pass 2 (k_out_v): out = v @ W2 via MFMA, swapped operands so each lane
//   stores one float4 per 16-col block.

#define DI 48

typedef __attribute__((ext_vector_type(8))) short short8;   // 8 bf16 = 4 VGPRs
typedef __attribute__((ext_vector_type(4))) float f32x4;

__device__ inline unsigned int pack_bf16(float lo, float hi) {
  __hip_bfloat162 h = __float22bfloat162_rn(make_float2(lo, hi));
  return *reinterpret_cast<unsigned int*>(&h);
}

constexpr int GB1 = 1024;  // k_gram_v blocks (4/CU)
constexpr int GB2 = 2048;  // k_out_v blocks  (8/CU)
constexpr int NC  = 32;    // G partial copies (atomic contention = GB1/NC per addr)
constexpr int SDT = 20;    // dwords per transposed bf16 column (16 row-pairs + pad)
constexpr int SDR = 28;    // dwords per row-major bf16 row (24 + pad, 16B-aligned)
constexpr int WDW = 48 * SDT + 32 * SDR;  // 1856 dwords per wave

// ---------------- K1: G = x^T x  +  v = x @ Wv^T  (+ closer epilogue) --------
__global__ __launch_bounds__(256) void k_gram_v(const float* __restrict__ x,
                                                const float* __restrict__ Wk,
                                                const float* __restrict__ Wq,
                                                const float* __restrict__ Wv,
                                                const float* __restrict__ Wo,
                                                float* __restrict__ G,
                                                int* __restrict__ cnt,
                                                __hip_bfloat16* __restrict__ Mt2,
                                                __hip_bfloat16* __restrict__ v,
                                                int N) {
  __shared__ unsigned int sh[4 * WDW];  // 29696 B; reused for reduce + epilogue
  __shared__ int sclose;
  const int tid = threadIdx.x;
  const int wave = tid >> 6, lane = tid & 63;
  unsigned int* xt = &sh[wave * WDW];       // transposed: [48 cols][SDT]
  unsigned int* xr = xt + 48 * SDT;         // row-major:  [32 rows][SDR]
  const int quad = lane >> 4, m = lane & 15;

  // Wv B-fragments for v = x@Wv^T: B[k=c][col=p] = Wv[p][c].
  short8 wv0 = {}, wv1 = {};
  if (m < 8) {
    const float* wrow = Wv + m * DI + 8 * quad;
    float4 c0 = *(const float4*)(wrow);
    float4 c1 = *(const float4*)(wrow + 4);
    unsigned int u0[4] = { pack_bf16(c0.x, c0.y), pack_bf16(c0.z, c0.w),
                           pack_bf16(c1.x, c1.y), pack_bf16(c1.z, c1.w) };
    wv0 = *(const short8*)u0;
    if (quad < 2) {
      float4 d0 = *(const float4*)(wrow + 32);
      float4 d1 = *(const float4*)(wrow + 36);
      unsigned int u1[4] = { pack_bf16(d0.x, d0.y), pack_bf16(d0.z, d0.w),
                             pack_bf16(d1.x, d1.y), pack_bf16(d1.z, d1.w) };
      wv1 = *(const short8*)u1;
    }
  }

  f32x4 acc[3][3] = {};

  const int rows_per_block = N / GB1;            // 1024
  const int rows_per_wave = rows_per_block >> 2; // 256
  const long long base0 = (long long)blockIdx.x * rows_per_block + wave * rows_per_wave;

  auto LOADT = [&](int tile, float4* va, float4* vb) {
#pragma unroll
    for (int s = 0; s < 3; ++s) {
      int task = lane + 64 * s;
      int rp = task / 12, cg = task % 12;
      const float4* p = (const float4*)(x + (base0 + tile * 32 + 2 * rp) * DI) + cg;
      va[s] = p[0];
      vb[s] = *(const float4*)((const float*)p + DI);
    }
  };

  auto PROCESS = [&](int tile, const float4* va, const float4* vb) {
    const long long rowt = base0 + (long long)tile * 32;
#pragma unroll
    for (int s = 0; s < 3; ++s) {
      int task = lane + 64 * s;
      int rp = task / 12, cg = task % 12;
      int c0 = 4 * cg;
      xt[(c0 + 0) * SDT + rp] = pack_bf16(va[s].x, vb[s].x);
      xt[(c0 + 1) * SDT + rp] = pack_bf16(va[s].y, vb[s].y);
      xt[(c0 + 2) * SDT + rp] = pack_bf16(va[s].z, vb[s].z);
      xt[(c0 + 3) * SDT + rp] = pack_bf16(va[s].w, vb[s].w);
      unsigned int ra[2] = { pack_bf16(va[s].x, va[s].y), pack_bf16(va[s].z, va[s].w) };
      unsigned int rb[2] = { pack_bf16(vb[s].x, vb[s].y), pack_bf16(vb[s].z, vb[s].w) };
      *(uint2*)&xr[(2 * rp) * SDR + 2 * cg]     = *(const uint2*)ra;
      *(uint2*)&xr[(2 * rp + 1) * SDR + 2 * cg] = *(const uint2*)rb;
    }
    asm volatile("s_waitcnt lgkmcnt(0)" ::: "memory");
    // Gram: single K=32 step
    short8 f[3];
#pragma unroll
    for (int t = 0; t < 3; ++t)
      f[t] = *(const short8*)&xt[(16 * t + m) * SDT + quad * 4];
#pragma unroll
    for (int i = 0; i < 3; ++i)
#pragma unroll
      for (int j = 0; j < 3; ++j)
        acc[i][j] = __builtin_amdgcn_mfma_f32_16x16x32_bf16(f[i], f[j], acc[i][j], 0, 0, 0);
    // v = x @ Wv^T for these 32 rows
#pragma unroll
    for (int g = 0; g < 2; ++g) {
      short8 a0 = *(const short8*)&xr[(16 * g + m) * SDR + quad * 4];
      short8 a1 = {};
      if (quad < 2) a1 = *(const short8*)&xr[(16 * g + m) * SDR + 16 + quad * 4];
      f32x4 vg = {};
      vg = __builtin_amdgcn_mfma_f32_16x16x32_bf16(a0, wv0, vg, 0, 0, 0);
      vg = __builtin_amdgcn_mfma_f32_16x16x32_bf16(a1, wv1, vg, 0, 0, 0);
      if (m < 8) {
        __hip_bfloat16* vr = v + (rowt + 16 * g + 4 * quad) * 8 + m;
#pragma unroll
        for (int r = 0; r < 4; ++r) vr[r * 8] = __float2bfloat16(vg[r]);
      }
    }
  };

  // ---- 8 tiles, 2-deep ping-pong prefetch ----
  float4 vaA[3], vbA[3], vaB[3], vbB[3];
  LOADT(0, vaA, vbA);
#pragma unroll
  for (int t = 0; t < 8; t += 2) {
    if (t + 1 < 8) LOADT(t + 1, vaB, vbB);
    PROCESS(t, vaA, vbA);
    if (t + 2 < 8) LOADT(t + 2, vaA, vbA);
    if (t + 1 < 8) PROCESS(t + 1, vaB, vbB);
  }

  // ---- cross-wave reduce through LDS, then 2304 atomics into copy blockIdx&31 ----
  __syncthreads();
  float* red = (float*)sh;
  if (wave >= 2) {
    float* dst = red + (wave - 2) * 2304 + lane * 36;
#pragma unroll
    for (int i = 0; i < 3; ++i)
#pragma unroll
      for (int j = 0; j < 3; ++j)
#pragma unroll
        for (int r = 0; r < 4; ++r) dst[(i * 3 + j) * 4 + r] = acc[i][j][r];
  }
  __syncthreads();
  if (wave < 2) {
    const float* s2 = red + wave * 2304 + lane * 36;
#pragma unroll
    for (int i = 0; i < 3; ++i)
#pragma unroll
      for (int j = 0; j < 3; ++j)
#pragma unroll
        for (int r = 0; r < 4; ++r) acc[i][j][r] += s2[(i * 3 + j) * 4 + r];
  }
  __syncthreads();
  if (wave == 1) {
    float* dst = red + lane * 36;
#pragma unroll
    for (int i = 0; i < 3; ++i)
#pragma unroll
      for (int j = 0; j < 3; ++j)
#pragma unroll
        for (int r = 0; r < 4; ++r) dst[(i * 3 + j) * 4 + r] = acc[i][j][r];
  }
  __syncthreads();
  if (wave == 0) {
    const float* s1 = red + lane * 36;
    float* Gp = G + (blockIdx.x & (NC - 1)) * 2304;
#pragma unroll
    for (int i = 0; i < 3; ++i)
#pragma unroll
      for (int j = 0; j < 3; ++j)
#pragma unroll
        for (int r = 0; r < 4; ++r) {
          float val = acc[i][j][r] + s1[(i * 3 + j) * 4 + r];
          atomicAdd(&Gp[(16 * i + quad * 4 + r) * 48 + 16 * j + m], val);
        }
  }

  // ---- last-block closer: epilogue (sum copies, softmax, W2 -> Mt2) ----
  __threadfence();          // release: our G atomics device-visible
  __syncthreads();
  if (tid == 0) {
    int old = atomicAdd(cnt, 1);
    sclose = (old == GB1 - 1) ? 1 : 0;
  }
  __syncthreads();
  if (!sclose) return;
  __threadfence();          // acquire: invalidate stale cached G lines

  {
    float* sG  = red;          // 2304
    float* sWk = red + 2304;   // 384
    float* sWq = red + 2688;   // 384
    float* sWo = red + 3072;   // 384
    float* sU  = red + 3456;   // 384
    float* sA  = red + 3840;   // 64
    for (int i = tid; i < 2304; i += 256) {
      float s = 0.f;
#pragma unroll
      for (int c = 0; c < NC; ++c) s += G[c * 2304 + i];
      sG[i] = s;
    }
    for (int i = tid; i < 384; i += 256) {
      sWk[i] = Wk[i]; sWq[i] = Wq[i]; sWo[i] = Wo[i];
    }
    __syncthreads();
    for (int e = tid; e < 384; e += 256) {
      int q = e & 7, i = e >> 3;
      float s = 0.f;
#pragma unroll
      for (int j = 0; j < 48; ++j) s += sG[i * 48 + j] * sWk[q * 48 + j];
      sU[q * 48 + i] = s;
    }
    __syncthreads();
    if (tid < 64) {  // wave 0: S[p][q] + row softmax over q
      int p = tid >> 3;
      float s = 0.f;
#pragma unroll
      for (int i = 0; i < 48; ++i) s += sWq[p * 48 + i] * sU[(tid & 7) * 48 + i];
      s *= 0.35355339059327373f;
      float mx = s;
      for (int d = 1; d < 8; d <<= 1) mx = fmaxf(mx, __shfl_xor(mx, d));
      float e = expf(s - mx);
      float den = e;
      for (int d = 1; d < 8; d <<= 1) den += __shfl_xor(den, d);
      sA[tid] = e / den;
    }
    __syncthreads();
    // Mt2[col*8+p] = bf16( sum_q sA[p*8+q] * Wo[col*8+q] )
    for (int e = tid; e < 384; e += 256) {
      int p = e & 7, col = e >> 3;
      float s = 0.f;
#pragma unroll
      for (int q = 0; q < 8; ++q) s += sA[p * 8 + q] * sWo[col * 8 + q];
      Mt2[col * 8 + p] = __float2bfloat16(s);
    }
  }
}

// ---------------- K2: out = v @ W2 (bf16 MFMA, swapped operands) ----------------
// A = W2^T frags (quad0 holds k=p<8, quads 1-3 zero pad), B = v^T frags.
// D[row=j][col=m] = out[rowg+m][16t+j] -> each lane stores one float4 per t.
__global__ __launch_bounds__(256) void k_out_v(const __hip_bfloat16* __restrict__ v,
                                               const __hip_bfloat16* __restrict__ Mt2,
                                               float* __restrict__ out, int N) {
  const int tid = threadIdx.x;
  const int wave = tid >> 6, lane = tid & 63;
  const int quad = lane >> 4, m = lane & 15;

  short8 b[3] = {short8{}, short8{}, short8{}};
  if (quad == 0) {
#pragma unroll
    for (int t = 0; t < 3; ++t)
      b[t] = *(const short8*)(Mt2 + (16 * t + m) * 8);  // A[j=m][p] = W2[p][16t+m]
  }

  const int rows_per_block = N / GB2;             // 512
  const int rows_per_wave = rows_per_block >> 2;  // 128
  const int ng = rows_per_wave >> 4;              // 8 groups of 16 rows
  const long long base = (long long)blockIdx.x * rows_per_block + wave * rows_per_wave;

  for (int g = 0; g < ng; ++g) {
    const long long rowg = base + (long long)g * 16;
    short8 af = {};
    if (quad == 0) af = *(const short8*)(v + (rowg + m) * 8);  // B[p][m] = v[rowg+m][p]
    f32x4 acc[3] = {};
#pragma unroll
    for (int t = 0; t < 3; ++t)
      acc[t] = __builtin_amdgcn_mfma_f32_16x16x32_bf16(b[t], af, acc[t], 0, 0, 0);
    float* orow = out + rowg * DI;
#pragma unroll
    for (int t = 0; t < 3; ++t)
      *(float4*)(orow + m * DI + 16 * t + 4 * quad) = *(const float4*)&acc[t];
  }
}

extern "C" void kernel_launch(void* const* d_in, const int* in_sizes, int n_in,
                              void* d_out, int out_size, void* d_ws, size_t ws_size,
                              hipStream_t stream) {
  const float* x  = (const float*)d_in[0];
  const float* Wk = (const float*)d_in[1];
  const float* Wq = (const float*)d_in[2];
  const float* Wv = (const float*)d_in[3];
  const float* Wo = (const float*)d_in[4];
  float* out = (float*)d_out;
  const int N = in_sizes[0] / DI;  // 1048576

  float* G = (float*)d_ws;                                        // 32*9216 B
  int* cnt = (int*)((char*)d_ws + 294912);                        // 4 B
  __hip_bfloat16* Mt2 = (__hip_bfloat16*)((char*)d_ws + 295936);  // 768 B
  __hip_bfloat16* v   = (__hip_bfloat16*)((char*)d_ws + 307200);  // N*16 B = 16.8 MB

  hipMemsetAsync(G, 0, NC * 2304 * sizeof(float) + 64, stream);   // G copies + cnt
  k_gram_v<<<GB1, 256, 0, stream>>>(x, Wk, Wq, Wv, Wo, G, cnt, Mt2, v, N);
  k_out_v<<<GB2, 256, 0, stream>>>(v, Mt2, out, N);
}

// Round 5
// 377.342 us; speedup vs baseline: 1.5470x; 1.5470x over previous
//
#include <hip/hip_runtime.h>
#include <hip/hip_bf16.h>

// N=1048576, D_IN=48, D_ATT=8
// Algebra: scores = Wq G Wk^T/sqrt(8), G = x^T x  [48x48]
//          v = x @ Wv^T  [N x 8]  (materialized bf16 in pass 1)
//          out = v @ W2, W2 = softmax(scores) Wo^T  [8x48]
// Pass 1 (k_gram_v): G via bf16 MFMA (atomics into ONE copy - proven
//   contention-free at 1024 blocks in round 1) + fused v=x@Wv^T.
// Pass 2 (k_out_v): every block redundantly computes the tiny epilogue
//   (G -> U -> softmax -> W2, ~2 us, L2-resident inputs) into LDS, then
//   out = v @ W2 via swapped-operand MFMA (float4 stores).
// Coherence: kernel boundary between the two kernels is the release/acquire
// point (implicit L2 flush at dispatch end). NO device fences (round-4 showed
// __threadfence => buffer_wbl2 storms => 3x slowdown).

#define DI 48

typedef __attribute__((ext_vector_type(8))) short short8;   // 8 bf16 = 4 VGPRs
typedef __attribute__((ext_vector_type(4))) float f32x4;

__device__ inline unsigned int pack_bf16(float lo, float hi) {
  __hip_bfloat162 h = __float22bfloat162_rn(make_float2(lo, hi));
  return *reinterpret_cast<unsigned int*>(&h);
}

constexpr int GB1 = 1024;  // k_gram_v blocks (4/CU)
constexpr int GB2 = 2048;  // k_out_v blocks  (8/CU)
constexpr int SDT = 20;    // dwords per transposed bf16 column (16 row-pairs + pad)
constexpr int SDR = 28;    // dwords per row-major bf16 row (24 + pad, 16B-aligned)
constexpr int WDW = 48 * SDT + 32 * SDR;  // 1856 dwords per wave

// ---------------- K1: G = x^T x  +  v = x @ Wv^T ----------------
__global__ __launch_bounds__(256) void k_gram_v(const float* __restrict__ x,
                                                const float* __restrict__ Wv,
                                                float* __restrict__ G,
                                                __hip_bfloat16* __restrict__ v,
                                                int N) {
  __shared__ unsigned int sh[4 * WDW];  // 29696 B; reused for reduction
  const int tid = threadIdx.x;
  const int wave = tid >> 6, lane = tid & 63;
  unsigned int* xt = &sh[wave * WDW];       // transposed: [48 cols][SDT]
  unsigned int* xr = xt + 48 * SDT;         // row-major:  [32 rows][SDR]
  const int quad = lane >> 4, m = lane & 15;

  // Wv B-fragments for v = x@Wv^T: B[k=c][col=p] = Wv[p][c].
  short8 wv0 = {}, wv1 = {};
  if (m < 8) {
    const float* wrow = Wv + m * DI + 8 * quad;
    float4 c0 = *(const float4*)(wrow);
    float4 c1 = *(const float4*)(wrow + 4);
    unsigned int u0[4] = { pack_bf16(c0.x, c0.y), pack_bf16(c0.z, c0.w),
                           pack_bf16(c1.x, c1.y), pack_bf16(c1.z, c1.w) };
    wv0 = *(const short8*)u0;
    if (quad < 2) {
      float4 d0 = *(const float4*)(wrow + 32);
      float4 d1 = *(const float4*)(wrow + 36);
      unsigned int u1[4] = { pack_bf16(d0.x, d0.y), pack_bf16(d0.z, d0.w),
                             pack_bf16(d1.x, d1.y), pack_bf16(d1.z, d1.w) };
      wv1 = *(const short8*)u1;
    }
  }

  f32x4 acc[3][3] = {};

  const int rows_per_block = N / GB1;            // 1024
  const int rows_per_wave = rows_per_block >> 2; // 256
  const long long base0 = (long long)blockIdx.x * rows_per_block + wave * rows_per_wave;

  auto LOADT = [&](int tile, float4* va, float4* vb) {
#pragma unroll
    for (int s = 0; s < 3; ++s) {
      int task = lane + 64 * s;
      int rp = task / 12, cg = task % 12;
      const float4* p = (const float4*)(x + (base0 + tile * 32 + 2 * rp) * DI) + cg;
      va[s] = p[0];
      vb[s] = *(const float4*)((const float*)p + DI);
    }
  };

  auto PROCESS = [&](int tile, const float4* va, const float4* vb) {
    const long long rowt = base0 + (long long)tile * 32;
#pragma unroll
    for (int s = 0; s < 3; ++s) {
      int task = lane + 64 * s;
      int rp = task / 12, cg = task % 12;
      int c0 = 4 * cg;
      xt[(c0 + 0) * SDT + rp] = pack_bf16(va[s].x, vb[s].x);
      xt[(c0 + 1) * SDT + rp] = pack_bf16(va[s].y, vb[s].y);
      xt[(c0 + 2) * SDT + rp] = pack_bf16(va[s].z, vb[s].z);
      xt[(c0 + 3) * SDT + rp] = pack_bf16(va[s].w, vb[s].w);
      unsigned int ra[2] = { pack_bf16(va[s].x, va[s].y), pack_bf16(va[s].z, va[s].w) };
      unsigned int rb[2] = { pack_bf16(vb[s].x, vb[s].y), pack_bf16(vb[s].z, vb[s].w) };
      *(uint2*)&xr[(2 * rp) * SDR + 2 * cg]     = *(const uint2*)ra;
      *(uint2*)&xr[(2 * rp + 1) * SDR + 2 * cg] = *(const uint2*)rb;
    }
    asm volatile("s_waitcnt lgkmcnt(0)" ::: "memory");
    // Gram: single K=32 step
    short8 f[3];
#pragma unroll
    for (int t = 0; t < 3; ++t)
      f[t] = *(const short8*)&xt[(16 * t + m) * SDT + quad * 4];
#pragma unroll
    for (int i = 0; i < 3; ++i)
#pragma unroll
      for (int j = 0; j < 3; ++j)
        acc[i][j] = __builtin_amdgcn_mfma_f32_16x16x32_bf16(f[i], f[j], acc[i][j], 0, 0, 0);
    // v = x @ Wv^T for these 32 rows
#pragma unroll
    for (int g = 0; g < 2; ++g) {
      short8 a0 = *(const short8*)&xr[(16 * g + m) * SDR + quad * 4];
      short8 a1 = {};
      if (quad < 2) a1 = *(const short8*)&xr[(16 * g + m) * SDR + 16 + quad * 4];
      f32x4 vg = {};
      vg = __builtin_amdgcn_mfma_f32_16x16x32_bf16(a0, wv0, vg, 0, 0, 0);
      vg = __builtin_amdgcn_mfma_f32_16x16x32_bf16(a1, wv1, vg, 0, 0, 0);
      if (m < 8) {
        __hip_bfloat16* vr = v + (rowt + 16 * g + 4 * quad) * 8 + m;
#pragma unroll
        for (int r = 0; r < 4; ++r) vr[r * 8] = __float2bfloat16(vg[r]);
      }
    }
  };

  // ---- 8 tiles, 2-deep ping-pong prefetch ----
  float4 vaA[3], vbA[3], vaB[3], vbB[3];
  LOADT(0, vaA, vbA);
#pragma unroll
  for (int t = 0; t < 8; t += 2) {
    if (t + 1 < 8) LOADT(t + 1, vaB, vbB);
    PROCESS(t, vaA, vbA);
    if (t + 2 < 8) LOADT(t + 2, vaA, vbA);
    if (t + 1 < 8) PROCESS(t + 1, vaB, vbB);
  }

  // ---- cross-wave reduce through LDS, then 2304 atomics (single G copy) ----
  __syncthreads();
  float* red = (float*)sh;
  if (wave >= 2) {
    float* dst = red + (wave - 2) * 2304 + lane * 36;
#pragma unroll
    for (int i = 0; i < 3; ++i)
#pragma unroll
      for (int j = 0; j < 3; ++j)
#pragma unroll
        for (int r = 0; r < 4; ++r) dst[(i * 3 + j) * 4 + r] = acc[i][j][r];
  }
  __syncthreads();
  if (wave < 2) {
    const float* s2 = red + wave * 2304 + lane * 36;
#pragma unroll
    for (int i = 0; i < 3; ++i)
#pragma unroll
      for (int j = 0; j < 3; ++j)
#pragma unroll
        for (int r = 0; r < 4; ++r) acc[i][j][r] += s2[(i * 3 + j) * 4 + r];
  }
  __syncthreads();
  if (wave == 1) {
    float* dst = red + lane * 36;
#pragma unroll
    for (int i = 0; i < 3; ++i)
#pragma unroll
      for (int j = 0; j < 3; ++j)
#pragma unroll
        for (int r = 0; r < 4; ++r) dst[(i * 3 + j) * 4 + r] = acc[i][j][r];
  }
  __syncthreads();
  if (wave == 0) {
    const float* s1 = red + lane * 36;
#pragma unroll
    for (int i = 0; i < 3; ++i)
#pragma unroll
      for (int j = 0; j < 3; ++j)
#pragma unroll
        for (int r = 0; r < 4; ++r) {
          float val = acc[i][j][r] + s1[(i * 3 + j) * 4 + r];
          atomicAdd(&G[(16 * i + quad * 4 + r) * 48 + 16 * j + m], val);
        }
  }
}

// ---------------- K2: per-block epilogue + out = v @ W2 ----------------
// Epilogue (every block, ~2 us, L2-resident): U = G Wk^T, S = Wq U /sqrt(8),
// softmax rows -> A, W2[p][col] = sum_q A[p][q] Wo[col][q] -> LDS bf16 table.
// Main: A = W2^T frags (quad0 holds k=p<8, quads 1-3 zero pad), B = v^T frags.
// D[row=j][col=m] = out[rowg+m][16t+j] -> each lane stores one float4 per t.
__global__ __launch_bounds__(256) void k_out_v(const __hip_bfloat16* __restrict__ v,
                                               const float* __restrict__ G,
                                               const float* __restrict__ Wk,
                                               const float* __restrict__ Wq,
                                               const float* __restrict__ Wo,
                                               float* __restrict__ out, int N) {
  __shared__ float sG[2304];
  __shared__ float sWk[384], sWq[384], sWo[384];
  __shared__ float sU[384];
  __shared__ float sA[64];
  __shared__ __hip_bfloat16 sMt[384];  // [col][p] bf16 fragment table
  const int tid = threadIdx.x;
  const int wave = tid >> 6, lane = tid & 63;
  const int quad = lane >> 4, m = lane & 15;

  // ---- epilogue ----
  for (int i = tid; i < 2304; i += 256) sG[i] = G[i];
  for (int i = tid; i < 384; i += 256) {
    sWk[i] = Wk[i]; sWq[i] = Wq[i]; sWo[i] = Wo[i];
  }
  __syncthreads();
  for (int e = tid; e < 384; e += 256) {
    int q = e & 7, i = e >> 3;
    float s = 0.f;
#pragma unroll
    for (int j = 0; j < 48; ++j) s += sG[i * 48 + j] * sWk[q * 48 + j];
    sU[q * 48 + i] = s;
  }
  __syncthreads();
  if (tid < 64) {  // wave 0: S[p][q] + row softmax over q
    int p = tid >> 3;
    float s = 0.f;
#pragma unroll
    for (int i = 0; i < 48; ++i) s += sWq[p * 48 + i] * sU[(tid & 7) * 48 + i];
    s *= 0.35355339059327373f;
    float mx = s;
    for (int d = 1; d < 8; d <<= 1) mx = fmaxf(mx, __shfl_xor(mx, d));
    float e = expf(s - mx);
    float den = e;
    for (int d = 1; d < 8; d <<= 1) den += __shfl_xor(den, d);
    sA[tid] = e / den;
  }
  __syncthreads();
  for (int e = tid; e < 384; e += 256) {
    int p = e & 7, col = e >> 3;
    float s = 0.f;
#pragma unroll
    for (int q = 0; q < 8; ++q) s += sA[p * 8 + q] * sWo[col * 8 + q];
    sMt[col * 8 + p] = __float2bfloat16(s);
  }
  __syncthreads();

  // ---- main loop ----
  short8 b[3] = {short8{}, short8{}, short8{}};
  if (quad == 0) {
#pragma unroll
    for (int t = 0; t < 3; ++t)
      b[t] = *(const short8*)(&sMt[(16 * t + m) * 8]);  // A[j=m][p] = W2[p][16t+m]
  }

  const int rows_per_block = N / GB2;             // 512
  const int rows_per_wave = rows_per_block >> 2;  // 128
  const int ng = rows_per_wave >> 4;              // 8 groups of 16 rows
  const long long base = (long long)blockIdx.x * rows_per_block + wave * rows_per_wave;

  for (int g = 0; g < ng; ++g) {
    const long long rowg = base + (long long)g * 16;
    short8 af = {};
    if (quad == 0) af = *(const short8*)(v + (rowg + m) * 8);  // B[p][m] = v[rowg+m][p]
    f32x4 acc[3] = {};
#pragma unroll
    for (int t = 0; t < 3; ++t)
      acc[t] = __builtin_amdgcn_mfma_f32_16x16x32_bf16(b[t], af, acc[t], 0, 0, 0);
    float* orow = out + rowg * DI;
#pragma unroll
    for (int t = 0; t < 3; ++t)
      *(float4*)(orow + m * DI + 16 * t + 4 * quad) = *(const float4*)&acc[t];
  }
}

extern "C" void kernel_launch(void* const* d_in, const int* in_sizes, int n_in,
                              void* d_out, int out_size, void* d_ws, size_t ws_size,
                              hipStream_t stream) {
  const float* x  = (const float*)d_in[0];
  const float* Wk = (const float*)d_in[1];
  const float* Wq = (const float*)d_in[2];
  const float* Wv = (const float*)d_in[3];
  const float* Wo = (const float*)d_in[4];
  float* out = (float*)d_out;
  const int N = in_sizes[0] / DI;  // 1048576

  float* G = (float*)d_ws;                                       // 9216 B
  __hip_bfloat16* v = (__hip_bfloat16*)((char*)d_ws + 16384);    // N*16 B = 16.8 MB

  hipMemsetAsync(G, 0, 2304 * sizeof(float), stream);
  k_gram_v<<<GB1, 256, 0, stream>>>(x, Wv, G, v, N);
  k_out_v<<<GB2, 256, 0, stream>>>(v, G, Wk, Wq, Wo, out, N);
}